// Round 12
// baseline (332.109 us; speedup 1.0000x reference)
//
#include <hip/hip_runtime.h>
#include <hip/hip_bf16.h>

#define Nn 20000
#define Ee 320000
#define Hh 4
#define Cc 128
#define HC 512
#define Gg 1024
#define NFt 9
#define EFt 4
#define GFt 50
#define EPSf 1e-5f
#define SLOPE 0.2f

typedef __attribute__((ext_vector_type(8))) short bf16x8;
typedef __attribute__((ext_vector_type(4))) float f32x4;
typedef __attribute__((ext_vector_type(2))) float f32x2;
typedef __attribute__((ext_vector_type(4))) unsigned ui32x4;

typedef const __attribute__((address_space(1))) unsigned char* gp1_t;
typedef __attribute__((address_space(3))) unsigned char* lp3_t;
__device__ __forceinline__ void gload16(const void* g, void* l) {
    __builtin_amdgcn_global_load_lds((gp1_t)g, (lp3_t)l, 16, 0, 0);
}

__device__ __forceinline__ float bf2f(short s) {
    return __uint_as_float(((unsigned)(unsigned short)s) << 16);
}
__device__ __forceinline__ float rfl(float v) {
    return __uint_as_float(__builtin_amdgcn_readfirstlane(__float_as_uint(v)));
}

// packed dual-FP32 VALU (CDNA3/4 VOP3P) — only fma/add/mul exist on gfx950
__device__ __forceinline__ f32x2 pkfma(f32x2 a, f32x2 b, f32x2 c) {
    f32x2 d;
    asm("v_pk_fma_f32 %0, %1, %2, %3" : "=v"(d) : "v"(a), "v"(b), "v"(c));
    return d;
}
__device__ __forceinline__ f32x2 pkadd(f32x2 a, f32x2 b) {
    f32x2 d;
    asm("v_pk_add_f32 %0, %1, %2" : "=v"(d) : "v"(a), "v"(b));
    return d;
}
__device__ __forceinline__ f32x2 pkmul(f32x2 a, f32x2 b) {
    f32x2 d;
    asm("v_pk_mul_f32 %0, %1, %2" : "=v"(d) : "v"(a), "v"(b));
    return d;
}

// ---------- merged setup: deg+rank | gofs | cvtW | xlxr1 ----------
__global__ __launch_bounds__(256) void k_setup(
    const int* __restrict__ dst, int* __restrict__ deg, int* __restrict__ rank,
    const int* __restrict__ batch, int* __restrict__ gofs,
    const float* __restrict__ Wl2, const float* __restrict__ Wr2,
    __hip_bfloat16* __restrict__ Wt,
    const float* __restrict__ x, const float* __restrict__ Wl1,
    const float* __restrict__ Wr1, __hip_bfloat16* __restrict__ xl,
    __hip_bfloat16* __restrict__ xr) {
    __shared__ float tile[64][65];
    int b = blockIdx.x, t = threadIdx.x;
    if (b < 1250) {  // deg count; returned old value = rank within dst segment
        int e = b * 256 + t;
        if (e < Ee) rank[e] = atomicAdd(&deg[dst[e]], 1);
    } else if (b < 1329) {  // graph offsets (batch sorted)
        int i = (b - 1250) * 256 + t;
        if (i >= Nn) return;
        int bb = batch[i];
        if (i == 0) {
            for (int g = 0; g <= bb; ++g) gofs[g] = 0;
        } else {
            int bp = batch[i - 1];
            for (int g = bp + 1; g <= bb; ++g) gofs[g] = i;
        }
        if (i == Nn - 1) {
            for (int g = bb + 1; g <= Gg; ++g) gofs[g] = Nn;
        }
    } else if (b < 1457) {  // W2 convert + transpose via LDS tile
        int tid = b - 1329;
        int tc = (tid >> 3) * 64;
        int tk = (tid & 7) * 64;
        int lc = t & 63, lr = t >> 6;
        const float* W = (tc < 512) ? Wl2 : Wr2;
        int cb = tc & 511;
#pragma unroll
        for (int i = 0; i < 16; ++i) {
            int r = lr * 16 + i;
            tile[r][lc] = W[(size_t)(tk + r) * 512 + cb + lc];
        }
        __syncthreads();
#pragma unroll
        for (int i = 0; i < 16; ++i) {
            int c = lr * 16 + i;
            Wt[(size_t)(tc + c) * 512 + tk + lc] = __float2bfloat16(tile[lc][c]);
        }
    } else {  // layer-1 transforms: wave per 2 nodes
        int l = t & 63, w = t >> 6;
        int ch0 = l * 8;
        int wid = (b - 1457) * 4 + w;
        int n0 = wid * 2, n1 = n0 + 1;
        float xa[NFt], xb[NFt];
#pragma unroll
        for (int f = 0; f < NFt; ++f) {
            xa[f] = x[n0 * NFt + f];
            xb[f] = x[n1 * NFt + f];
        }
        float a0[8] = {}, r0[8] = {}, a1[8] = {}, r1[8] = {};
#pragma unroll
        for (int f = 0; f < NFt; ++f) {
            f32x4 wl0 = *(const f32x4*)&Wl1[f * HC + ch0];
            f32x4 wl1 = *(const f32x4*)&Wl1[f * HC + ch0 + 4];
            f32x4 wr0 = *(const f32x4*)&Wr1[f * HC + ch0];
            f32x4 wr1 = *(const f32x4*)&Wr1[f * HC + ch0 + 4];
#pragma unroll
            for (int k = 0; k < 4; ++k) {
                a0[k] = fmaf(xa[f], wl0[k], a0[k]);
                a0[k + 4] = fmaf(xa[f], wl1[k], a0[k + 4]);
                r0[k] = fmaf(xa[f], wr0[k], r0[k]);
                r0[k + 4] = fmaf(xa[f], wr1[k], r0[k + 4]);
                a1[k] = fmaf(xb[f], wl0[k], a1[k]);
                a1[k + 4] = fmaf(xb[f], wl1[k], a1[k + 4]);
                r1[k] = fmaf(xb[f], wr0[k], r1[k]);
                r1[k + 4] = fmaf(xb[f], wr1[k], r1[k + 4]);
            }
        }
        auto cvt8 = [](const float* v) {
            bf16x8 o;
#pragma unroll
            for (int k = 0; k < 8; ++k) {
                union { float f; unsigned u; } cv;
                cv.f = v[k];
                unsigned r = (cv.u + 0x7fff + ((cv.u >> 16) & 1)) >> 16;
                o[k] = (short)r;
            }
            return o;
        };
        *(bf16x8*)(xl + (size_t)n0 * HC + ch0) = cvt8(a0);
        *(bf16x8*)(xr + (size_t)n0 * HC + ch0) = cvt8(r0);
        *(bf16x8*)(xl + (size_t)n1 * HC + ch0) = cvt8(a1);
        *(bf16x8*)(xr + (size_t)n1 * HC + ch0) = cvt8(r1);
    }
}

// ---------- one-block exclusive scan of deg -> rowptr ----------
__global__ void k_scan(const int* __restrict__ deg, int* __restrict__ rowptr) {
    __shared__ int sums[1024];
    int t = threadIdx.x;
    const int n = Nn;
    int chunk = (n + 1023) / 1024;
    int start = t * chunk;
    int lim = min(start + chunk, n);
    int s = 0;
    for (int i = start; i < lim; ++i) s += deg[i];
    sums[t] = s;
    __syncthreads();
    for (int off = 1; off < 1024; off <<= 1) {
        int v = (t >= off) ? sums[t - off] : 0;
        __syncthreads();
        sums[t] += v;
        __syncthreads();
    }
    int run = (t == 0) ? 0 : sums[t - 1];
    for (int i = start; i < lim; ++i) { rowptr[i] = run; run += deg[i]; }
    if (t == 1023) rowptr[n] = sums[1023];
}

// ---------- scatter without atomics: pos = rowptr[dst] + rank ----------
__global__ void k_scatter(const int* __restrict__ src, const int* __restrict__ dst,
                          const float* __restrict__ ea, const int* __restrict__ rowptr,
                          const int* __restrict__ rank, int* __restrict__ csr_src,
                          float4* __restrict__ ea_s) {
    int e = blockIdx.x * 256 + threadIdx.x;
    if (e >= Ee) return;
    int pos = rowptr[dst[e]] + rank[e];
    csr_src[pos] = src[e];
    ea_s[pos] = ((const float4*)ea)[e];
}

// ---------- fused bf16 MFMA GEMM: [xl|xr][M x 1024] = h[M x 512] @ Wt^T ----------
__global__ __launch_bounds__(256) void k_gemm_mfma(const short* __restrict__ Abf,
                                                   const short* __restrict__ Bt,
                                                   __hip_bfloat16* __restrict__ xl,
                                                   __hip_bfloat16* __restrict__ xr, int M) {
    __shared__ short As[128 * 32];
    __shared__ short Bs[128 * 32];
    int tid = threadIdx.x;
    int l = tid & 63;
    int wid = tid >> 6;
    int bm0 = blockIdx.x * 128;
    int bn0 = blockIdx.y * 128;
    int wr = (wid >> 1) * 64;
    int wc = (wid & 1) * 64;
    f32x4 acc[4][4] = {};

    int srow = l >> 2;
    int skoff = ((l & 3) ^ ((l >> 3) & 3)) * 8;
    int rk = (((l >> 4) ^ (l >> 1)) & 3) * 8;

    for (int k0 = 0; k0 < 512; k0 += 32) {
        {
            int c = wid;
            long row = min(bm0 + c * 16 + srow, M - 1);
            gload16(Abf + row * 512 + k0 + skoff, &As[c * 512]);
            int col = bn0 + c * 16 + srow;
            gload16(Bt + (size_t)col * 512 + k0 + skoff, &Bs[c * 512]);
            c = wid + 4;
            row = min(bm0 + c * 16 + srow, M - 1);
            gload16(Abf + row * 512 + k0 + skoff, &As[c * 512]);
            col = bn0 + c * 16 + srow;
            gload16(Bt + (size_t)col * 512 + k0 + skoff, &Bs[c * 512]);
        }
        asm volatile("s_waitcnt vmcnt(0)" ::: "memory");
        __syncthreads();
        bf16x8 af[4], bfr[4];
#pragma unroll
        for (int m = 0; m < 4; ++m)
            af[m] = *(const bf16x8*)&As[(wr + m * 16 + (l & 15)) * 32 + rk];
#pragma unroll
        for (int n = 0; n < 4; ++n)
            bfr[n] = *(const bf16x8*)&Bs[(wc + n * 16 + (l & 15)) * 32 + rk];
#pragma unroll
        for (int m = 0; m < 4; ++m)
#pragma unroll
            for (int n = 0; n < 4; ++n)
                acc[m][n] = __builtin_amdgcn_mfma_f32_16x16x32_bf16(af[m], bfr[n],
                                                                    acc[m][n], 0, 0, 0);
        __syncthreads();
    }
    __hip_bfloat16* dst = (bn0 < 512) ? xl : xr;
    int cb = bn0 & 511;
#pragma unroll
    for (int m = 0; m < 4; ++m) {
#pragma unroll
        for (int n = 0; n < 4; ++n) {
            int col = cb + wc + n * 16 + (l & 15);
#pragma unroll
            for (int r = 0; r < 4; ++r) {
                int row = bm0 + wr + m * 16 + (l >> 4) * 4 + r;
                if (row < M) dst[(size_t)row * 512 + col] = __float2bfloat16(acc[m][n][r]);
            }
        }
    }
}

// ---------- fused attention: 2 nodes/wave, hoisted prologue, r8 chunk pipeline ----------
__global__ __launch_bounds__(256) void k_fused_attn(
    const __hip_bfloat16* __restrict__ xl, const __hip_bfloat16* __restrict__ xr,
    const float* __restrict__ We, const float* __restrict__ att,
    const int* __restrict__ rowptr, const int* __restrict__ csr_src,
    const float4* __restrict__ ea_s, const float* __restrict__ bias,
    const float* __restrict__ gamma, const float* __restrict__ beta,
    const float* __restrict__ mean, const float* __restrict__ var,
    __hip_bfloat16* __restrict__ hout) {
    int l = threadIdx.x & 63;
    int wid = blockIdx.x * 4 + (threadIdx.x >> 6);  // 0..9999
    int ch0 = l * 8;

    // ---- wave-invariant prologue (amortized over 2 nodes) ----
    f32x2 wee2[4][4], ar2[4];
#pragma unroll
    for (int f = 0; f < 4; ++f) {
        f32x4 w0 = *(const f32x4*)&We[f * HC + ch0];
        f32x4 w1 = *(const f32x4*)&We[f * HC + ch0 + 4];
        wee2[f][0] = (f32x2){w0.x, w0.y};
        wee2[f][1] = (f32x2){w0.z, w0.w};
        wee2[f][2] = (f32x2){w1.x, w1.y};
        wee2[f][3] = (f32x2){w1.z, w1.w};
    }
    {
        f32x4 a0 = *(const f32x4*)&att[ch0];
        f32x4 a1 = *(const f32x4*)&att[ch0 + 4];
        ar2[0] = (f32x2){a0.x, a0.y};
        ar2[1] = (f32x2){a0.z, a0.w};
        ar2[2] = (f32x2){a1.x, a1.y};
        ar2[3] = (f32x2){a1.z, a1.w};
    }
    // BN folded: out = relu(acc*iden*S + O)
    float S[8], O[8];
    {
        f32x4 bi0 = *(const f32x4*)&bias[ch0], bi1 = *(const f32x4*)&bias[ch0 + 4];
        f32x4 ga0 = *(const f32x4*)&gamma[ch0], ga1 = *(const f32x4*)&gamma[ch0 + 4];
        f32x4 be0 = *(const f32x4*)&beta[ch0], be1 = *(const f32x4*)&beta[ch0 + 4];
        f32x4 me0 = *(const f32x4*)&mean[ch0], me1 = *(const f32x4*)&mean[ch0 + 4];
        f32x4 va0 = *(const f32x4*)&var[ch0], va1 = *(const f32x4*)&var[ch0 + 4];
#pragma unroll
        for (int k = 0; k < 8; ++k) {
            float bik = (k < 4) ? bi0[k] : bi1[k - 4];
            float gak = (k < 4) ? ga0[k] : ga1[k - 4];
            float bek = (k < 4) ? be0[k] : be1[k - 4];
            float mek = (k < 4) ? me0[k] : me1[k - 4];
            float vak = (k < 4) ? va0[k] : va1[k - 4];
            S[k] = gak * rsqrtf(vak + EPSf);
            O[k] = (bik - mek) * S[k] + bek;
        }
    }

#pragma unroll 1
    for (int n = wid * 2; n < wid * 2 + 2; ++n) {
        f32x2 rr2[4];
        {
            ui32x4 ru = *(const ui32x4*)(xr + (size_t)n * HC + ch0);
#pragma unroll
            for (int j = 0; j < 4; ++j) {
                unsigned u = ru[j];
                rr2[j] = (f32x2){__uint_as_float(u << 16),
                                 __uint_as_float(u & 0xffff0000u)};
            }
        }
        int start = __builtin_amdgcn_readfirstlane(rowptr[n]);
        int nedge = __builtin_amdgcn_readfirstlane(rowptr[n + 1]) - start;
        int last = start + nedge - 1;

        float m = -1e30f, den = 0.f;
        f32x2 acc2[4] = {};
        float es0 = 0.f, es1 = 0.f, es2 = 0.f, es3 = 0.f;

        struct Chunk {
            int s[4];
            float e[4][4];
            bf16x8 x[4];
        };

        auto accum4 = [&](const Chunk& c, const float* ex) {
#pragma unroll
            for (int i = 0; i < 4; ++i) {
                f32x2 esp = (f32x2){ex[i], ex[i]};
                ui32x4 xu = *(const ui32x4*)&c.x[i];
#pragma unroll
                for (int j = 0; j < 4; ++j) {
                    unsigned u = xu[j];
                    f32x2 xv = (f32x2){__uint_as_float(u << 16),
                                       __uint_as_float(u & 0xffff0000u)};
                    acc2[j] = pkfma(esp, xv, acc2[j]);
                }
            }
        };

        auto step = [&](Chunk& cur, Chunk& nxt, int base) {
            // prefetch next chunk meta (SGPR) + gathers (issued before compute)
#pragma unroll
            for (int i = 0; i < 4; ++i) {
                int idx = min(start + base + 4 + i, last);
                nxt.s[i] = __builtin_amdgcn_readfirstlane(csr_src[idx]);
                float4 v = ea_s[idx];
                nxt.e[i][0] = rfl(v.x); nxt.e[i][1] = rfl(v.y);
                nxt.e[i][2] = rfl(v.z); nxt.e[i][3] = rfl(v.w);
            }
#pragma unroll
            for (int i = 0; i < 4; ++i)
                nxt.x[i] = *(const bf16x8*)(xl + (size_t)nxt.s[i] * HC + ch0);

#pragma unroll
            for (int i = 0; i < 4; ++i) {
                if (base + i < nedge) {
                    es0 += cur.e[i][0]; es1 += cur.e[i][1];
                    es2 += cur.e[i][2]; es3 += cur.e[i][3];
                }
            }

            float p[4];
#pragma unroll
            for (int i = 0; i < 4; ++i) {
                ui32x4 xu = *(const ui32x4*)&cur.x[i];
                f32x2 e0p = (f32x2){cur.e[i][0], cur.e[i][0]};
                f32x2 e1p = (f32x2){cur.e[i][1], cur.e[i][1]};
                f32x2 e2p = (f32x2){cur.e[i][2], cur.e[i][2]};
                f32x2 e3p = (f32x2){cur.e[i][3], cur.e[i][3]};
                f32x2 plin = (f32x2){0.f, 0.f}, pabs = (f32x2){0.f, 0.f};
#pragma unroll
                for (int j = 0; j < 4; ++j) {
                    unsigned u = xu[j];
                    f32x2 xv = (f32x2){__uint_as_float(u << 16),
                                       __uint_as_float(u & 0xffff0000u)};
                    f32x2 z = pkadd(xv, rr2[j]);
                    z = pkfma(e0p, wee2[0][j], z);
                    z = pkfma(e1p, wee2[1][j], z);
                    z = pkfma(e2p, wee2[2][j], z);
                    z = pkfma(e3p, wee2[3][j], z);
                    f32x2 za = (f32x2){fabsf(z.x), fabsf(z.y)};
                    plin = pkfma(ar2[j], z, plin);
                    pabs = pkfma(ar2[j], za, pabs);
                }
                // leaky(z) = 0.6z + 0.4|z| -> att-dot = linear + abs parts
                p[i] = 0.6f * (plin.x + plin.y) + 0.4f * (pabs.x + pabs.y);
            }
#pragma unroll
            for (int off = 8; off; off >>= 1) {  // 16-lane (per-head) butterfly
                p[0] += __shfl_xor(p[0], off);
                p[1] += __shfl_xor(p[1], off);
                p[2] += __shfl_xor(p[2], off);
                p[3] += __shfl_xor(p[3], off);
            }
#pragma unroll
            for (int i = 1; i < 4; ++i)
                if (base + i >= nedge) p[i] = -1e30f;

            float pmax = fmaxf(fmaxf(p[0], p[1]), fmaxf(p[2], p[3]));
            float ex[4];
            if (__all(pmax <= m + 8.f)) {
                // defer-max: skip rescale (values bounded by e^8)
                ex[0] = __expf(p[0] - m); ex[1] = __expf(p[1] - m);
                ex[2] = __expf(p[2] - m); ex[3] = __expf(p[3] - m);
                den += ex[0] + ex[1] + ex[2] + ex[3];
                accum4(cur, ex);
            } else {
                float mn = fmaxf(m, pmax);
                float sc = __expf(m - mn);
                ex[0] = __expf(p[0] - mn); ex[1] = __expf(p[1] - mn);
                ex[2] = __expf(p[2] - mn); ex[3] = __expf(p[3] - mn);
                den = den * sc + ex[0] + ex[1] + ex[2] + ex[3];
                f32x2 scs = (f32x2){sc, sc};
#pragma unroll
                for (int j = 0; j < 4; ++j) acc2[j] = pkmul(acc2[j], scs);
                accum4(cur, ex);
                m = mn;
            }
        };

        if (nedge > 0) {
            Chunk A, B;
#pragma unroll
            for (int i = 0; i < 4; ++i) {
                int idx = min(start + i, last);
                A.s[i] = __builtin_amdgcn_readfirstlane(csr_src[idx]);
                float4 v = ea_s[idx];
                A.e[i][0] = rfl(v.x); A.e[i][1] = rfl(v.y);
                A.e[i][2] = rfl(v.z); A.e[i][3] = rfl(v.w);
            }
#pragma unroll
            for (int i = 0; i < 4; ++i)
                A.x[i] = *(const bf16x8*)(xl + (size_t)A.s[i] * HC + ch0);

            int base = 0;
            for (;;) {
                step(A, B, base);
                base += 4;
                if (base >= nedge) break;
                step(B, A, base);
                base += 4;
                if (base >= nedge) break;
            }
        }

        // ----- self-loop item (ea mean from running sum) -----
        {
            float dv = (float)max(nedge, 1);
            float e0 = es0 / dv, e1 = es1 / dv, e2 = es2 / dv, e3 = es3 / dv;
            ui32x4 xu = *(const ui32x4*)(xl + (size_t)n * HC + ch0);
            f32x2 e0p = (f32x2){e0, e0}, e1p = (f32x2){e1, e1};
            f32x2 e2p = (f32x2){e2, e2}, e3p = (f32x2){e3, e3};
            f32x2 plin = (f32x2){0.f, 0.f}, pabs = (f32x2){0.f, 0.f};
            f32x2 xv2[4];
#pragma unroll
            for (int j = 0; j < 4; ++j) {
                unsigned u = xu[j];
                xv2[j] = (f32x2){__uint_as_float(u << 16),
                                 __uint_as_float(u & 0xffff0000u)};
                f32x2 z = pkadd(xv2[j], rr2[j]);
                z = pkfma(e0p, wee2[0][j], z);
                z = pkfma(e1p, wee2[1][j], z);
                z = pkfma(e2p, wee2[2][j], z);
                z = pkfma(e3p, wee2[3][j], z);
                f32x2 za = (f32x2){fabsf(z.x), fabsf(z.y)};
                plin = pkfma(ar2[j], z, plin);
                pabs = pkfma(ar2[j], za, pabs);
            }
            float pi = 0.6f * (plin.x + plin.y) + 0.4f * (pabs.x + pabs.y);
#pragma unroll
            for (int off = 8; off; off >>= 1) pi += __shfl_xor(pi, off);
            float mn = fmaxf(m, pi);
            float sc = __expf(m - mn);
            float ex = __expf(pi - mn);
            den = den * sc + ex;
            f32x2 scs = (f32x2){sc, sc};
            f32x2 exs = (f32x2){ex, ex};
#pragma unroll
            for (int j = 0; j < 4; ++j)
                acc2[j] = pkfma(exs, xv2[j], pkmul(acc2[j], scs));
        }

        // ----- epilogue: folded BN + ReLU, bf16 out -----
        float iden = 1.f / den;
        float aflat[8] = {acc2[0].x, acc2[0].y, acc2[1].x, acc2[1].y,
                          acc2[2].x, acc2[2].y, acc2[3].x, acc2[3].y};
        bf16x8 ob;
#pragma unroll
        for (int k = 0; k < 8; ++k) {
            float v = fmaxf(fmaf(aflat[k] * iden, S[k], O[k]), 0.f);
            union { float f; unsigned u; } cv;
            cv.f = v;
            unsigned r = (cv.u + 0x7fff + ((cv.u >> 16) & 1)) >> 16;
            ob[k] = (short)r;
        }
        *(bf16x8*)(hout + (size_t)n * HC + ch0) = ob;
    }
}

// ---------- fused mean-pool (bf16 h) + MLP ----------
__global__ __launch_bounds__(256) void k_pool_mlp(
    const __hip_bfloat16* __restrict__ h, const int* __restrict__ gofs,
    const float* __restrict__ gfeat, const float* __restrict__ fc1w,
    const float* __restrict__ fc1b, const float* __restrict__ fc2w,
    const float* __restrict__ fc2b, float* __restrict__ out) {
    __shared__ float z[HC + GFt];
    __shared__ float red[256];
    int g = blockIdx.x, t = threadIdx.x;
    int s = gofs[g], e = gofs[g + 1];
    float a0 = 0.f, a1 = 0.f;
    for (int r = s; r < e; ++r) {
        ushort2 v = ((const ushort2*)(h + (size_t)r * HC))[t];
        a0 += bf2f((short)v.x);
        a1 += bf2f((short)v.y);
    }
    float ic = (e > s) ? 1.f / (float)(e - s) : 0.f;
    z[2 * t] = a0 * ic;
    z[2 * t + 1] = a1 * ic;
    if (t < GFt) z[HC + t] = gfeat[g * GFt + t];
    __syncthreads();
    int c = t & 127, half = t >> 7;
    float acc = (half == 0) ? fc1b[c] : 0.f;
    int j0 = half * 281, j1 = j0 + 281;
    for (int j = j0; j < j1; ++j) acc += z[j] * fc1w[j * 128 + c];
    red[t] = acc;
    __syncthreads();
    if (t < 128) {
        float a = red[t] + red[t + 128];
        red[t] = fmaxf(a, 0.f) * fc2w[t];
    }
    __syncthreads();
    for (int off = 64; off; off >>= 1) {
        if (t < off) red[t] += red[t + off];
        __syncthreads();
    }
    if (t == 0) out[g] = red[0] + fc2b[0];
}

extern "C" void kernel_launch(void* const* d_in, const int* in_sizes, int n_in,
                              void* d_out, int out_size, void* d_ws, size_t ws_size,
                              hipStream_t stream) {
    const float* x = (const float*)d_in[0];
    const float* ea = (const float*)d_in[1];
    const float* gfeat = (const float*)d_in[2];
    const float* Wl1 = (const float*)d_in[3];
    const float* Wr1 = (const float*)d_in[4];
    const float* We1 = (const float*)d_in[5];
    const float* att1 = (const float*)d_in[6];
    const float* b1 = (const float*)d_in[7];
    const float* gamma1 = (const float*)d_in[8];
    const float* beta1 = (const float*)d_in[9];
    const float* mean1 = (const float*)d_in[10];
    const float* var1 = (const float*)d_in[11];
    const float* Wl2 = (const float*)d_in[12];
    const float* Wr2 = (const float*)d_in[13];
    const float* We2 = (const float*)d_in[14];
    const float* att2 = (const float*)d_in[15];
    const float* b2 = (const float*)d_in[16];
    const float* gamma2 = (const float*)d_in[17];
    const float* beta2 = (const float*)d_in[18];
    const float* mean2 = (const float*)d_in[19];
    const float* var2 = (const float*)d_in[20];
    const float* fc1w = (const float*)d_in[21];
    const float* fc1b = (const float*)d_in[22];
    const float* fc2w = (const float*)d_in[23];
    const float* fc2b = (const float*)d_in[24];
    const int* eidx = (const int*)d_in[25];
    const int* batch = (const int*)d_in[26];
    float* out = (float*)d_out;

    const int* srcp = eidx;
    const int* dstp = eidx + Ee;

    char* p = (char*)d_ws;
    auto alloc = [&](size_t bytes) -> char* {
        char* r = p;
        p += (bytes + 255) & ~(size_t)255;
        return r;
    };
    __hip_bfloat16* xl = (__hip_bfloat16*)alloc((size_t)Nn * HC * 2);
    __hip_bfloat16* xr = (__hip_bfloat16*)alloc((size_t)Nn * HC * 2);
    __hip_bfloat16* h_bf = (__hip_bfloat16*)alloc((size_t)Nn * HC * 2);
    int* deg = (int*)alloc((size_t)Nn * 4);
    int* rank = (int*)alloc((size_t)Ee * 4);
    int* rowptr = (int*)alloc((size_t)(Nn + 1) * 4);
    int* csr_src = (int*)alloc((size_t)Ee * 4);
    float4* ea_s = (float4*)alloc((size_t)Ee * 16);
    int* gofs = (int*)alloc((size_t)(Gg + 1) * 4);
    __hip_bfloat16* Wt = (__hip_bfloat16*)alloc((size_t)1024 * 512 * 2);

    hipMemsetAsync(deg, 0, (size_t)Nn * 4, stream);

    k_setup<<<1457 + 2500, 256, 0, stream>>>(dstp, deg, rank, batch, gofs, Wl2, Wr2,
                                             Wt, x, Wl1, Wr1, xl, xr);
    k_scan<<<1, 1024, 0, stream>>>(deg, rowptr);
    k_scatter<<<(Ee + 255) / 256, 256, 0, stream>>>(srcp, dstp, ea, rowptr, rank,
                                                    csr_src, ea_s);

    // ----- layer 1 -----
    k_fused_attn<<<2500, 256, 0, stream>>>(xl, xr, We1, att1, rowptr, csr_src,
                                           ea_s, b1, gamma1, beta1, mean1, var1,
                                           h_bf);

    // ----- layer 2 -----
    k_gemm_mfma<<<dim3((Nn + 127) / 128, 8), 256, 0, stream>>>(
        (const short*)h_bf, (const short*)Wt, xl, xr, Nn);
    k_fused_attn<<<2500, 256, 0, stream>>>(xl, xr, We2, att2, rowptr, csr_src,
                                           ea_s, b2, gamma2, beta2, mean2, var2,
                                           h_bf);

    // ----- pooling + MLP -----
    k_pool_mlp<<<Gg, 256, 0, stream>>>(h_bf, gofs, gfeat, fc1w, fc1b, fc2w, fc2b, out);
}

// Round 13
// 316.761 us; speedup vs baseline: 1.0485x; 1.0485x over previous
//
#include <hip/hip_runtime.h>
#include <hip/hip_bf16.h>

#define Nn 20000
#define Ee 320000
#define Hh 4
#define Cc 128
#define HC 512
#define Gg 1024
#define NFt 9
#define EFt 4
#define GFt 50
#define EPSf 1e-5f
#define SLOPE 0.2f

typedef __attribute__((ext_vector_type(8))) short bf16x8;
typedef __attribute__((ext_vector_type(4))) float f32x4;
typedef __attribute__((ext_vector_type(2))) float f32x2;
typedef __attribute__((ext_vector_type(4))) unsigned ui32x4;

typedef const __attribute__((address_space(1))) unsigned char* gp1_t;
typedef __attribute__((address_space(3))) unsigned char* lp3_t;
__device__ __forceinline__ void gload16(const void* g, void* l) {
    __builtin_amdgcn_global_load_lds((gp1_t)g, (lp3_t)l, 16, 0, 0);
}

__device__ __forceinline__ float bf2f(short s) {
    return __uint_as_float(((unsigned)(unsigned short)s) << 16);
}
__device__ __forceinline__ float rfl(float v) {
    return __uint_as_float(__builtin_amdgcn_readfirstlane(__float_as_uint(v)));
}

// packed dual-FP32 VALU (CDNA3/4 VOP3P) — only fma/add/mul exist on gfx950
__device__ __forceinline__ f32x2 pkfma(f32x2 a, f32x2 b, f32x2 c) {
    f32x2 d;
    asm("v_pk_fma_f32 %0, %1, %2, %3" : "=v"(d) : "v"(a), "v"(b), "v"(c));
    return d;
}
__device__ __forceinline__ f32x2 pkadd(f32x2 a, f32x2 b) {
    f32x2 d;
    asm("v_pk_add_f32 %0, %1, %2" : "=v"(d) : "v"(a), "v"(b));
    return d;
}
__device__ __forceinline__ f32x2 pkmul(f32x2 a, f32x2 b) {
    f32x2 d;
    asm("v_pk_mul_f32 %0, %1, %2" : "=v"(d) : "v"(a), "v"(b));
    return d;
}

// ---------- merged setup: deg+rank | gofs | cvtW | xlxr1 ----------
__global__ __launch_bounds__(256) void k_setup(
    const int* __restrict__ dst, int* __restrict__ deg, int* __restrict__ rank,
    const int* __restrict__ batch, int* __restrict__ gofs,
    const float* __restrict__ Wl2, const float* __restrict__ Wr2,
    __hip_bfloat16* __restrict__ Wt,
    const float* __restrict__ x, const float* __restrict__ Wl1,
    const float* __restrict__ Wr1, __hip_bfloat16* __restrict__ xl,
    __hip_bfloat16* __restrict__ xr) {
    __shared__ float tile[64][65];
    int b = blockIdx.x, t = threadIdx.x;
    if (b < 1250) {  // deg count; returned old value = rank within dst segment
        int e = b * 256 + t;
        if (e < Ee) rank[e] = atomicAdd(&deg[dst[e]], 1);
    } else if (b < 1329) {  // graph offsets (batch sorted)
        int i = (b - 1250) * 256 + t;
        if (i >= Nn) return;
        int bb = batch[i];
        if (i == 0) {
            for (int g = 0; g <= bb; ++g) gofs[g] = 0;
        } else {
            int bp = batch[i - 1];
            for (int g = bp + 1; g <= bb; ++g) gofs[g] = i;
        }
        if (i == Nn - 1) {
            for (int g = bb + 1; g <= Gg; ++g) gofs[g] = Nn;
        }
    } else if (b < 1457) {  // W2 convert + transpose via LDS tile
        int tid = b - 1329;
        int tc = (tid >> 3) * 64;
        int tk = (tid & 7) * 64;
        int lc = t & 63, lr = t >> 6;
        const float* W = (tc < 512) ? Wl2 : Wr2;
        int cb = tc & 511;
#pragma unroll
        for (int i = 0; i < 16; ++i) {
            int r = lr * 16 + i;
            tile[r][lc] = W[(size_t)(tk + r) * 512 + cb + lc];
        }
        __syncthreads();
#pragma unroll
        for (int i = 0; i < 16; ++i) {
            int c = lr * 16 + i;
            Wt[(size_t)(tc + c) * 512 + tk + lc] = __float2bfloat16(tile[lc][c]);
        }
    } else {  // layer-1 transforms: wave per 2 nodes
        int l = t & 63, w = t >> 6;
        int ch0 = l * 8;
        int wid = (b - 1457) * 4 + w;
        int n0 = wid * 2, n1 = n0 + 1;
        float xa[NFt], xb[NFt];
#pragma unroll
        for (int f = 0; f < NFt; ++f) {
            xa[f] = x[n0 * NFt + f];
            xb[f] = x[n1 * NFt + f];
        }
        float a0[8] = {}, r0[8] = {}, a1[8] = {}, r1[8] = {};
#pragma unroll
        for (int f = 0; f < NFt; ++f) {
            f32x4 wl0 = *(const f32x4*)&Wl1[f * HC + ch0];
            f32x4 wl1 = *(const f32x4*)&Wl1[f * HC + ch0 + 4];
            f32x4 wr0 = *(const f32x4*)&Wr1[f * HC + ch0];
            f32x4 wr1 = *(const f32x4*)&Wr1[f * HC + ch0 + 4];
#pragma unroll
            for (int k = 0; k < 4; ++k) {
                a0[k] = fmaf(xa[f], wl0[k], a0[k]);
                a0[k + 4] = fmaf(xa[f], wl1[k], a0[k + 4]);
                r0[k] = fmaf(xa[f], wr0[k], r0[k]);
                r0[k + 4] = fmaf(xa[f], wr1[k], r0[k + 4]);
                a1[k] = fmaf(xb[f], wl0[k], a1[k]);
                a1[k + 4] = fmaf(xb[f], wl1[k], a1[k + 4]);
                r1[k] = fmaf(xb[f], wr0[k], r1[k]);
                r1[k + 4] = fmaf(xb[f], wr1[k], r1[k + 4]);
            }
        }
        auto cvt8 = [](const float* v) {
            bf16x8 o;
#pragma unroll
            for (int k = 0; k < 8; ++k) {
                union { float f; unsigned u; } cv;
                cv.f = v[k];
                unsigned r = (cv.u + 0x7fff + ((cv.u >> 16) & 1)) >> 16;
                o[k] = (short)r;
            }
            return o;
        };
        *(bf16x8*)(xl + (size_t)n0 * HC + ch0) = cvt8(a0);
        *(bf16x8*)(xr + (size_t)n0 * HC + ch0) = cvt8(r0);
        *(bf16x8*)(xl + (size_t)n1 * HC + ch0) = cvt8(a1);
        *(bf16x8*)(xr + (size_t)n1 * HC + ch0) = cvt8(r1);
    }
}

// ---------- one-block exclusive scan of deg -> rowptr ----------
__global__ void k_scan(const int* __restrict__ deg, int* __restrict__ rowptr) {
    __shared__ int sums[1024];
    int t = threadIdx.x;
    const int n = Nn;
    int chunk = (n + 1023) / 1024;
    int start = t * chunk;
    int lim = min(start + chunk, n);
    int s = 0;
    for (int i = start; i < lim; ++i) s += deg[i];
    sums[t] = s;
    __syncthreads();
    for (int off = 1; off < 1024; off <<= 1) {
        int v = (t >= off) ? sums[t - off] : 0;
        __syncthreads();
        sums[t] += v;
        __syncthreads();
    }
    int run = (t == 0) ? 0 : sums[t - 1];
    for (int i = start; i < lim; ++i) { rowptr[i] = run; run += deg[i]; }
    if (t == 1023) rowptr[n] = sums[1023];
}

// ---------- scatter without atomics: pos = rowptr[dst] + rank ----------
__global__ void k_scatter(const int* __restrict__ src, const int* __restrict__ dst,
                          const float* __restrict__ ea, const int* __restrict__ rowptr,
                          const int* __restrict__ rank, int* __restrict__ csr_src,
                          float4* __restrict__ ea_s) {
    int e = blockIdx.x * 256 + threadIdx.x;
    if (e >= Ee) return;
    int pos = rowptr[dst[e]] + rank[e];
    csr_src[pos] = src[e];
    ea_s[pos] = ((const float4*)ea)[e];
}

// ---------- fused bf16 MFMA GEMM: [xl|xr][M x 1024] = h[M x 512] @ Wt^T ----------
__global__ __launch_bounds__(256) void k_gemm_mfma(const short* __restrict__ Abf,
                                                   const short* __restrict__ Bt,
                                                   __hip_bfloat16* __restrict__ xl,
                                                   __hip_bfloat16* __restrict__ xr, int M) {
    __shared__ short As[128 * 32];
    __shared__ short Bs[128 * 32];
    int tid = threadIdx.x;
    int l = tid & 63;
    int wid = tid >> 6;
    int bm0 = blockIdx.x * 128;
    int bn0 = blockIdx.y * 128;
    int wr = (wid >> 1) * 64;
    int wc = (wid & 1) * 64;
    f32x4 acc[4][4] = {};

    int srow = l >> 2;
    int skoff = ((l & 3) ^ ((l >> 3) & 3)) * 8;
    int rk = (((l >> 4) ^ (l >> 1)) & 3) * 8;

    for (int k0 = 0; k0 < 512; k0 += 32) {
        {
            int c = wid;
            long row = min(bm0 + c * 16 + srow, M - 1);
            gload16(Abf + row * 512 + k0 + skoff, &As[c * 512]);
            int col = bn0 + c * 16 + srow;
            gload16(Bt + (size_t)col * 512 + k0 + skoff, &Bs[c * 512]);
            c = wid + 4;
            row = min(bm0 + c * 16 + srow, M - 1);
            gload16(Abf + row * 512 + k0 + skoff, &As[c * 512]);
            col = bn0 + c * 16 + srow;
            gload16(Bt + (size_t)col * 512 + k0 + skoff, &Bs[c * 512]);
        }
        asm volatile("s_waitcnt vmcnt(0)" ::: "memory");
        __syncthreads();
        bf16x8 af[4], bfr[4];
#pragma unroll
        for (int m = 0; m < 4; ++m)
            af[m] = *(const bf16x8*)&As[(wr + m * 16 + (l & 15)) * 32 + rk];
#pragma unroll
        for (int n = 0; n < 4; ++n)
            bfr[n] = *(const bf16x8*)&Bs[(wc + n * 16 + (l & 15)) * 32 + rk];
#pragma unroll
        for (int m = 0; m < 4; ++m)
#pragma unroll
            for (int n = 0; n < 4; ++n)
                acc[m][n] = __builtin_amdgcn_mfma_f32_16x16x32_bf16(af[m], bfr[n],
                                                                    acc[m][n], 0, 0, 0);
        __syncthreads();
    }
    __hip_bfloat16* dst = (bn0 < 512) ? xl : xr;
    int cb = bn0 & 511;
#pragma unroll
    for (int m = 0; m < 4; ++m) {
#pragma unroll
        for (int n = 0; n < 4; ++n) {
            int col = cb + wc + n * 16 + (l & 15);
#pragma unroll
            for (int r = 0; r < 4; ++r) {
                int row = bm0 + wr + m * 16 + (l >> 4) * 4 + r;
                if (row < M) dst[(size_t)row * 512 + col] = __float2bfloat16(acc[m][n][r]);
            }
        }
    }
}

// ---------- fused attention: 1 wave/node, depth-2 pipeline (split issue/commit) ----------
// r8's step() stalled on meta loads (issue -> immediate readfirstlane). Here the
// meta loads for chunk b+12 are ISSUED one iteration before their rfl COMMIT, so
// both meta latency and gather latency are covered by a full compute phase.
__global__ __launch_bounds__(256) void k_fused_attn(
    const __hip_bfloat16* __restrict__ xl, const __hip_bfloat16* __restrict__ xr,
    const float* __restrict__ We, const float* __restrict__ att,
    const int* __restrict__ rowptr, const int* __restrict__ csr_src,
    const float4* __restrict__ ea_s, const float* __restrict__ bias,
    const float* __restrict__ gamma, const float* __restrict__ beta,
    const float* __restrict__ mean, const float* __restrict__ var,
    __hip_bfloat16* __restrict__ hout) {
    int n = blockIdx.x * 4 + (threadIdx.x >> 6);
    if (n >= Nn) return;
    int l = threadIdx.x & 63;
    int ch0 = l * 8;

    f32x2 wee2[4][4], ar2[4], rr2[4];
#pragma unroll
    for (int f = 0; f < 4; ++f) {
        f32x4 w0 = *(const f32x4*)&We[f * HC + ch0];
        f32x4 w1 = *(const f32x4*)&We[f * HC + ch0 + 4];
        wee2[f][0] = (f32x2){w0.x, w0.y};
        wee2[f][1] = (f32x2){w0.z, w0.w};
        wee2[f][2] = (f32x2){w1.x, w1.y};
        wee2[f][3] = (f32x2){w1.z, w1.w};
    }
    {
        f32x4 a0 = *(const f32x4*)&att[ch0];
        f32x4 a1 = *(const f32x4*)&att[ch0 + 4];
        ar2[0] = (f32x2){a0.x, a0.y};
        ar2[1] = (f32x2){a0.z, a0.w};
        ar2[2] = (f32x2){a1.x, a1.y};
        ar2[3] = (f32x2){a1.z, a1.w};
    }
    {
        ui32x4 ru = *(const ui32x4*)(xr + (size_t)n * HC + ch0);
#pragma unroll
        for (int j = 0; j < 4; ++j) {
            unsigned u = ru[j];
            rr2[j] = (f32x2){__uint_as_float(u << 16), __uint_as_float(u & 0xffff0000u)};
        }
    }

    int start = __builtin_amdgcn_readfirstlane(rowptr[n]);
    int nedge = __builtin_amdgcn_readfirstlane(rowptr[n + 1]) - start;
    int last = start + nedge - 1;

    float m = -1e30f, den = 0.f;
    f32x2 acc2[4] = {};
    float es0 = 0.f, es1 = 0.f, es2 = 0.f, es3 = 0.f;

    struct MetaV {  // in-flight meta loads (VGPRs, uniform values)
        int s[4];
        float4 e[4];
    };
    struct MetaS {  // committed meta (SGPRs after readfirstlane)
        int s[4];
        float e[4][4];
    };
    struct Xc {  // per-chunk compute state
        float e[4][4];
        bf16x8 x[4];
    };

    auto issue_meta = [&](MetaV& mv, int b4) {
#pragma unroll
        for (int i = 0; i < 4; ++i) {
            int idx = min(start + b4 + i, last);
            mv.s[i] = csr_src[idx];
            mv.e[i] = ea_s[idx];
        }
    };
    auto commit_meta = [&](MetaS& ms, const MetaV& mv) {
#pragma unroll
        for (int i = 0; i < 4; ++i) {
            ms.s[i] = __builtin_amdgcn_readfirstlane(mv.s[i]);
            ms.e[i][0] = rfl(mv.e[i].x);
            ms.e[i][1] = rfl(mv.e[i].y);
            ms.e[i][2] = rfl(mv.e[i].z);
            ms.e[i][3] = rfl(mv.e[i].w);
        }
    };
    auto gather = [&](Xc& X, const MetaS& ms) {
#pragma unroll
        for (int i = 0; i < 4; ++i) {
            X.x[i] = *(const bf16x8*)(xl + (size_t)ms.s[i] * HC + ch0);
#pragma unroll
            for (int j = 0; j < 4; ++j) X.e[i][j] = ms.e[i][j];
        }
    };
    auto compute = [&](const Xc& C, int base) {
#pragma unroll
        for (int i = 0; i < 4; ++i) {
            if (base + i < nedge) {
                es0 += C.e[i][0]; es1 += C.e[i][1];
                es2 += C.e[i][2]; es3 += C.e[i][3];
            }
        }
        float p[4];
#pragma unroll
        for (int i = 0; i < 4; ++i) {
            ui32x4 xu = *(const ui32x4*)&C.x[i];
            f32x2 e0p = (f32x2){C.e[i][0], C.e[i][0]};
            f32x2 e1p = (f32x2){C.e[i][1], C.e[i][1]};
            f32x2 e2p = (f32x2){C.e[i][2], C.e[i][2]};
            f32x2 e3p = (f32x2){C.e[i][3], C.e[i][3]};
            f32x2 plin = (f32x2){0.f, 0.f}, pabs = (f32x2){0.f, 0.f};
#pragma unroll
            for (int j = 0; j < 4; ++j) {
                unsigned u = xu[j];
                f32x2 xv = (f32x2){__uint_as_float(u << 16),
                                   __uint_as_float(u & 0xffff0000u)};
                f32x2 z = pkadd(xv, rr2[j]);
                z = pkfma(e0p, wee2[0][j], z);
                z = pkfma(e1p, wee2[1][j], z);
                z = pkfma(e2p, wee2[2][j], z);
                z = pkfma(e3p, wee2[3][j], z);
                f32x2 za = (f32x2){fabsf(z.x), fabsf(z.y)};
                plin = pkfma(ar2[j], z, plin);
                pabs = pkfma(ar2[j], za, pabs);
            }
            // leaky(z) = 0.6z + 0.4|z| -> att-dot = linear + abs parts
            p[i] = 0.6f * (plin.x + plin.y) + 0.4f * (pabs.x + pabs.y);
        }
#pragma unroll
        for (int off = 8; off; off >>= 1) {  // 16-lane (per-head) butterfly
            p[0] += __shfl_xor(p[0], off);
            p[1] += __shfl_xor(p[1], off);
            p[2] += __shfl_xor(p[2], off);
            p[3] += __shfl_xor(p[3], off);
        }
#pragma unroll
        for (int i = 1; i < 4; ++i)
            if (base + i >= nedge) p[i] = -1e30f;

        float pmax = fmaxf(fmaxf(p[0], p[1]), fmaxf(p[2], p[3]));
        float ex[4];
        float mloc = m;
        if (!__all(pmax <= mloc + 8.f)) {  // defer-max: rescale only when needed
            float mn = fmaxf(mloc, pmax);
            float sc = __expf(mloc - mn);
            den *= sc;
            f32x2 scs = (f32x2){sc, sc};
#pragma unroll
            for (int j = 0; j < 4; ++j) acc2[j] = pkmul(acc2[j], scs);
            m = mn;
            mloc = mn;
        }
        ex[0] = __expf(p[0] - mloc); ex[1] = __expf(p[1] - mloc);
        ex[2] = __expf(p[2] - mloc); ex[3] = __expf(p[3] - mloc);
        den += ex[0] + ex[1] + ex[2] + ex[3];
#pragma unroll
        for (int i = 0; i < 4; ++i) {
            f32x2 esp = (f32x2){ex[i], ex[i]};
            ui32x4 xu = *(const ui32x4*)&C.x[i];
#pragma unroll
            for (int j = 0; j < 4; ++j) {
                unsigned u = xu[j];
                f32x2 xv = (f32x2){__uint_as_float(u << 16),
                                   __uint_as_float(u & 0xffff0000u)};
                acc2[j] = pkfma(esp, xv, acc2[j]);
            }
        }
    };

    if (nedge > 0) {
        MetaV mvi;
        MetaS msN;
        Xc XA, XB;
        // prologue: XA <- chunk 0; msN <- meta(4); mvi <- loads for meta(8)
        issue_meta(mvi, 0);
        {
            MetaS ms0;
            commit_meta(ms0, mvi);  // unavoidable first-stall
            issue_meta(mvi, 4);
            gather(XA, ms0);
        }
        commit_meta(msN, mvi);  // meta(4), partially covered by XA gathers
        issue_meta(mvi, 8);

        int base = 0;
        for (;;) {
            // invariant: XA = chunk base; msN = meta(base+4); mvi = loads(base+8)
            gather(XB, msN);             // issue gathers for base+4
            commit_meta(msN, mvi);       // meta(base+8); loads covered by last compute
            issue_meta(mvi, base + 12);  // in flight across this compute
            compute(XA, base);
            base += 4;
            if (base >= nedge) break;
            gather(XA, msN);
            commit_meta(msN, mvi);
            issue_meta(mvi, base + 12);
            compute(XB, base);
            base += 4;
            if (base >= nedge) break;
        }
    }

    // ----- self-loop item (ea mean from running sum) -----
    {
        float dv = (float)max(nedge, 1);
        float e0 = es0 / dv, e1 = es1 / dv, e2 = es2 / dv, e3 = es3 / dv;
        ui32x4 xu = *(const ui32x4*)(xl + (size_t)n * HC + ch0);
        f32x2 e0p = (f32x2){e0, e0}, e1p = (f32x2){e1, e1};
        f32x2 e2p = (f32x2){e2, e2}, e3p = (f32x2){e3, e3};
        f32x2 plin = (f32x2){0.f, 0.f}, pabs = (f32x2){0.f, 0.f};
        f32x2 xv2[4];
#pragma unroll
        for (int j = 0; j < 4; ++j) {
            unsigned u = xu[j];
            xv2[j] = (f32x2){__uint_as_float(u << 16), __uint_as_float(u & 0xffff0000u)};
            f32x2 z = pkadd(xv2[j], rr2[j]);
            z = pkfma(e0p, wee2[0][j], z);
            z = pkfma(e1p, wee2[1][j], z);
            z = pkfma(e2p, wee2[2][j], z);
            z = pkfma(e3p, wee2[3][j], z);
            f32x2 za = (f32x2){fabsf(z.x), fabsf(z.y)};
            plin = pkfma(ar2[j], z, plin);
            pabs = pkfma(ar2[j], za, pabs);
        }
        float pi = 0.6f * (plin.x + plin.y) + 0.4f * (pabs.x + pabs.y);
#pragma unroll
        for (int off = 8; off; off >>= 1) pi += __shfl_xor(pi, off);
        float mn = fmaxf(m, pi);
        float sc = __expf(m - mn);
        float ex = __expf(pi - mn);
        den = den * sc + ex;
        f32x2 scs = (f32x2){sc, sc};
        f32x2 exs = (f32x2){ex, ex};
#pragma unroll
        for (int j = 0; j < 4; ++j) acc2[j] = pkfma(exs, xv2[j], pkmul(acc2[j], scs));
    }

    // ----- epilogue: folded BN + ReLU, bf16 out -----
    float iden = 1.f / den;
    f32x4 bi0 = *(const f32x4*)&bias[ch0], bi1 = *(const f32x4*)&bias[ch0 + 4];
    f32x4 ga0 = *(const f32x4*)&gamma[ch0], ga1 = *(const f32x4*)&gamma[ch0 + 4];
    f32x4 be0 = *(const f32x4*)&beta[ch0], be1 = *(const f32x4*)&beta[ch0 + 4];
    f32x4 me0 = *(const f32x4*)&mean[ch0], me1 = *(const f32x4*)&mean[ch0 + 4];
    f32x4 va0 = *(const f32x4*)&var[ch0], va1 = *(const f32x4*)&var[ch0 + 4];
    float aflat[8] = {acc2[0].x, acc2[0].y, acc2[1].x, acc2[1].y,
                      acc2[2].x, acc2[2].y, acc2[3].x, acc2[3].y};
    bf16x8 ob;
#pragma unroll
    for (int k = 0; k < 8; ++k) {
        float bik = (k < 4) ? bi0[k] : bi1[k - 4];
        float gak = (k < 4) ? ga0[k] : ga1[k - 4];
        float bek = (k < 4) ? be0[k] : be1[k - 4];
        float mek = (k < 4) ? me0[k] : me1[k - 4];
        float vak = (k < 4) ? va0[k] : va1[k - 4];
        float Sk = gak * rsqrtf(vak + EPSf);
        float Ok = (bik - mek) * Sk + bek;
        float v = fmaxf(fmaf(aflat[k] * iden, Sk, Ok), 0.f);
        union { float f; unsigned u; } cv;
        cv.f = v;
        unsigned r = (cv.u + 0x7fff + ((cv.u >> 16) & 1)) >> 16;
        ob[k] = (short)r;
    }
    *(bf16x8*)(hout + (size_t)n * HC + ch0) = ob;
}

// ---------- fused mean-pool (bf16 h) + MLP ----------
__global__ __launch_bounds__(256) void k_pool_mlp(
    const __hip_bfloat16* __restrict__ h, const int* __restrict__ gofs,
    const float* __restrict__ gfeat, const float* __restrict__ fc1w,
    const float* __restrict__ fc1b, const float* __restrict__ fc2w,
    const float* __restrict__ fc2b, float* __restrict__ out) {
    __shared__ float z[HC + GFt];
    __shared__ float red[256];
    int g = blockIdx.x, t = threadIdx.x;
    int s = gofs[g], e = gofs[g + 1];
    float a0 = 0.f, a1 = 0.f;
    for (int r = s; r < e; ++r) {
        ushort2 v = ((const ushort2*)(h + (size_t)r * HC))[t];
        a0 += bf2f((short)v.x);
        a1 += bf2f((short)v.y);
    }
    float ic = (e > s) ? 1.f / (float)(e - s) : 0.f;
    z[2 * t] = a0 * ic;
    z[2 * t + 1] = a1 * ic;
    if (t < GFt) z[HC + t] = gfeat[g * GFt + t];
    __syncthreads();
    int c = t & 127, half = t >> 7;
    float acc = (half == 0) ? fc1b[c] : 0.f;
    int j0 = half * 281, j1 = j0 + 281;
    for (int j = j0; j < j1; ++j) acc += z[j] * fc1w[j * 128 + c];
    red[t] = acc;
    __syncthreads();
    if (t < 128) {
        float a = red[t] + red[t + 128];
        red[t] = fmaxf(a, 0.f) * fc2w[t];
    }
    __syncthreads();
    for (int off = 64; off; off >>= 1) {
        if (t < off) red[t] += red[t + off];
        __syncthreads();
    }
    if (t == 0) out[g] = red[0] + fc2b[0];
}

extern "C" void kernel_launch(void* const* d_in, const int* in_sizes, int n_in,
                              void* d_out, int out_size, void* d_ws, size_t ws_size,
                              hipStream_t stream) {
    const float* x = (const float*)d_in[0];
    const float* ea = (const float*)d_in[1];
    const float* gfeat = (const float*)d_in[2];
    const float* Wl1 = (const float*)d_in[3];
    const float* Wr1 = (const float*)d_in[4];
    const float* We1 = (const float*)d_in[5];
    const float* att1 = (const float*)d_in[6];
    const float* b1 = (const float*)d_in[7];
    const float* gamma1 = (const float*)d_in[8];
    const float* beta1 = (const float*)d_in[9];
    const float* mean1 = (const float*)d_in[10];
    const float* var1 = (const float*)d_in[11];
    const float* Wl2 = (const float*)d_in[12];
    const float* Wr2 = (const float*)d_in[13];
    const float* We2 = (const float*)d_in[14];
    const float* att2 = (const float*)d_in[15];
    const float* b2 = (const float*)d_in[16];
    const float* gamma2 = (const float*)d_in[17];
    const float* beta2 = (const float*)d_in[18];
    const float* mean2 = (const float*)d_in[19];
    const float* var2 = (const float*)d_in[20];
    const float* fc1w = (const float*)d_in[21];
    const float* fc1b = (const float*)d_in[22];
    const float* fc2w = (const float*)d_in[23];
    const float* fc2b = (const float*)d_in[24];
    const int* eidx = (const int*)d_in[25];
    const int* batch = (const int*)d_in[26];
    float* out = (float*)d_out;

    const int* srcp = eidx;
    const int* dstp = eidx + Ee;

    char* p = (char*)d_ws;
    auto alloc = [&](size_t bytes) -> char* {
        char* r = p;
        p += (bytes + 255) & ~(size_t)255;
        return r;
    };
    __hip_bfloat16* xl = (__hip_bfloat16*)alloc((size_t)Nn * HC * 2);
    __hip_bfloat16* xr = (__hip_bfloat16*)alloc((size_t)Nn * HC * 2);
    __hip_bfloat16* h_bf = (__hip_bfloat16*)alloc((size_t)Nn * HC * 2);
    int* deg = (int*)alloc((size_t)Nn * 4);
    int* rank = (int*)alloc((size_t)Ee * 4);
    int* rowptr = (int*)alloc((size_t)(Nn + 1) * 4);
    int* csr_src = (int*)alloc((size_t)Ee * 4);
    float4* ea_s = (float4*)alloc((size_t)Ee * 16);
    int* gofs = (int*)alloc((size_t)(Gg + 1) * 4);
    __hip_bfloat16* Wt = (__hip_bfloat16*)alloc((size_t)1024 * 512 * 2);

    hipMemsetAsync(deg, 0, (size_t)Nn * 4, stream);

    k_setup<<<1457 + 2500, 256, 0, stream>>>(dstp, deg, rank, batch, gofs, Wl2, Wr2,
                                             Wt, x, Wl1, Wr1, xl, xr);
    k_scan<<<1, 1024, 0, stream>>>(deg, rowptr);
    k_scatter<<<(Ee + 255) / 256, 256, 0, stream>>>(srcp, dstp, ea, rowptr, rank,
                                                    csr_src, ea_s);

    // ----- layer 1 -----
    k_fused_attn<<<5000, 256, 0, stream>>>(xl, xr, We1, att1, rowptr, csr_src,
                                           ea_s, b1, gamma1, beta1, mean1, var1,
                                           h_bf);

    // ----- layer 2 -----
    k_gemm_mfma<<<dim3((Nn + 127) / 128, 8), 256, 0, stream>>>(
        (const short*)h_bf, (const short*)Wt, xl, xr, Nn);
    k_fused_attn<<<5000, 256, 0, stream>>>(xl, xr, We2, att2, rowptr, csr_src,
                                           ea_s, b2, gamma2, beta2, mean2, var2,
                                           h_bf);

    // ----- pooling + MLP -----
    k_pool_mlp<<<Gg, 256, 0, stream>>>(h_bf, gofs, gfeat, fc1w, fc1b, fc2w, fc2b, out);
}